// Round 4
// baseline (176.418 us; speedup 1.0000x reference)
//
#include <hip/hip_runtime.h>
#include <math.h>

// Problem constants (match reference)
#define B_    256
#define T_    4096
#define N_    8        // n
#define TWON_ 16       // 2n
#define H_    64
#define P_    144      // 2n + 2n^2
#define WBLK  64                 // one wave per block
#define NBLKX (T_ / WBLK)        // 64 blocks along T
#define NPART (NBLKX * B_)       // 16384 partials
#define PSTRIDE 20               // LDS row stride in half2 units: 80 B rows, 16B-aligned
#define FBLK  1024               // finalize block size

// denominators
#define INV_MAIN  (1.0f / (float)(B_ * TWON_ * T_))   // 1/16777216
#define INV_SUP   (1.0f / (float)(B_ * (P_ + TWON_))) // 1/40960

#define TWO_LOG2E 2.8853900817779268f   // 2*log2(e): e^{2x} = 2^{x*TWO_LOG2E}

// ---- Session conclusions baked in (r1-r15) ----
// * 1-wave blocks, lb(64,6): best measured total (127.5-127.9 us). 2-wave
//   lb(128,6) neutral; lb(128,8) VGPR-capped to 64 -> 221 MB spills (r10);
//   2-chunk amortization kept setup regs live across epilogue -> spills (r8).
// * NEVER same-address atomicAdd from 16k blocks: serial convoy, +190 us (r9).
// * r12/r13 REGRESSION: 16 VGPRs of x_target live across the WHOLE MFMA
//   phase + zw/zb in LDS -> allocator collapse (VGPR_Count=40, 315 MB scratch
//   writes, main 22->139 us). zw/zb MUST stay in registers; x_target regs
//   must be short-lived.
// * r14: r0 structure + packed f32x2 physics epilogue -> 127.46 us (neutral,
//   within noise). Verified clean: main kernel below top-5, fills at 78-83%.
// * r15 (this): per-TILE JIT x_target dwordx4 in C-layout (4 transient regs,
//   consumed same iteration), observable+data-loss fused in-tile (f32),
//   epilogue drops relu+16 strided loads+data loss. Removes the pre-barrier
//   16-load vmcnt(0) drain (~900 cy/wave unhidden). lo/hi activation split
//   offsets the +4 transient regs.
// * Remaining total is harness-dominated: 268 MB ws poison fill (~40 us @ 83%
//   HBM peak), input restores, launch gaps. Main kernel vs its ~11 us
//   x_target-read floor is the only lever.

typedef __fp16   half2_t __attribute__((ext_vector_type(2)));  // cvt_pkrtz result type
typedef _Float16 half8_t __attribute__((ext_vector_type(8)));  // MFMA operand type
typedef float    f32x4   __attribute__((ext_vector_type(4)));
typedef float    f32x2   __attribute__((ext_vector_type(2)));

union HPack { half2_t h2[4]; half8_t h8; };   // MFMA operand pun
union RPack { uint4 u4[4]; half2_t h2[16]; }; // LDS row read pun (64 B)

__device__ __forceinline__ float wave_reduce(float v) {
    #pragma unroll
    for (int off = 32; off > 0; off >>= 1) v += __shfl_down(v, off, 64);
    return v;
}

__global__ __launch_bounds__(WBLK, 6)
void pinn_main_kernel(const float* __restrict__ t_in,
                      const float* __restrict__ x_target,
                      const float* __restrict__ params_pred,
                      const float* __restrict__ params_target,
                      const float* __restrict__ ic_pred,
                      const float* __restrict__ ic_target,
                      const float* __restrict__ W1,
                      const float* __restrict__ b1,
                      const float* __restrict__ W2,
                      const float* __restrict__ b2,
                      float* __restrict__ partials) {
    __shared__ __align__(16) half2_t spk[WBLK * PSTRIDE];  // 5.1 KB: (obs, dobs) packed

    const int lane = threadIdx.x;    // 0..63
    const int b    = blockIdx.y;
    const int q    = lane >> 4;      // quad
    const int mn   = lane & 15;      // A-row (point-in-tile) == B/C col n
    const int k0   = q * 8;          // this lane's k-group base (within K=32 half)

    const float* pp = params_pred + b * P_;   // uniform -> scalar loads
    const int tq = blockIdx.x * WBLK + lane;

    // ---- supervised loss (blocks with x==0; one per batch) ----
    float sup = 0.0f;
    if (blockIdx.x == 0) {
        #pragma unroll
        for (int i = lane; i < P_; i += WBLK) {   // 144 elems
            const float d = pp[i] - params_target[b * P_ + i];
            sup = fmaf(d, d, sup);
        }
        if (lane < TWON_) {
            const float d = ic_pred[b * TWON_ + lane] - ic_target[b * TWON_ + lane];
            sup = fmaf(d, d, sup);
        }
    }

    // ---- per-lane weight setup (REGISTERS — r12 lesson: not LDS) ----
    // E = e^{2x} = exp2(x*2log2e); tanh = 1 - 2/(E+1). exp2 limits give h=+-1, g=0.
    float zwlo[8], zblo[8], zwhi[8], zbhi[8];
    HPack Blo, Bhi, Plo, Phi;   // B[k][n]=W2[k][n]; B'[k][n]=W1[k]*W2[k][n]
    #pragma unroll
    for (int j2 = 0; j2 < 4; ++j2) {
        const int ka = k0 + 2 * j2, kb = ka + 1;
        const float w1a = W1[ka],      w1b = W1[kb];
        const float w1c = W1[32 + ka], w1d = W1[32 + kb];
        zwlo[2*j2] = TWO_LOG2E * w1a; zwlo[2*j2+1] = TWO_LOG2E * w1b;
        zwhi[2*j2] = TWO_LOG2E * w1c; zwhi[2*j2+1] = TWO_LOG2E * w1d;
        zblo[2*j2] = TWO_LOG2E * b1[ka];      zblo[2*j2+1] = TWO_LOG2E * b1[kb];
        zbhi[2*j2] = TWO_LOG2E * b1[32 + ka]; zbhi[2*j2+1] = TWO_LOG2E * b1[32 + kb];
        const float wa = W2[ka * TWON_ + mn],        wb = W2[kb * TWON_ + mn];
        const float wc = W2[(32 + ka) * TWON_ + mn], wd = W2[(32 + kb) * TWON_ + mn];
        Blo.h2[j2] = __builtin_amdgcn_cvt_pkrtz(wa, wb);
        Bhi.h2[j2] = __builtin_amdgcn_cvt_pkrtz(wc, wd);
        Plo.h2[j2] = __builtin_amdgcn_cvt_pkrtz(w1a * wa, w1b * wb);
        Phi.h2[j2] = __builtin_amdgcn_cvt_pkrtz(w1c * wc, w1d * wd);
    }
    const float b2n   = b2[mn];
    const float mucol = pp[mn];        // == mu[mn-8] when mn>=8 (pp[8..15] is mu)
    const bool  isq   = (mn >= 8);

    // t for this wave's 64 points
    const float treg = t_in[b * T_ + tq];

    // x_target C-layout row base for this lane: row (=2n index) mn, cols 4q..
    const float* xrow = x_target + ((size_t)b * TWON_ + mn) * T_
                        + blockIdx.x * WBLK + 4 * q;

    float dacc = 0.0f;   // data-loss accumulator (C layout, f32)

    // ---- 4 tiles of 16 points each ----
    #pragma unroll
    for (int ti = 0; ti < 4; ++ti) {
        // per-tile JIT x_target load: 4 TRANSIENT regs, consumed at tile end.
        // (r12 lesson: never 16 regs live across the whole phase.)
        const float4 xt4 = *(const float4*)(xrow + ti * 16);

        const float tt = __shfl(treg, ti * 16 + mn, 64);

        f32x4 lat = {b2n, b2n, b2n, b2n};
        f32x4 dl  = {0.0f, 0.0f, 0.0f, 0.0f};

        // lo pass then hi pass reusing the same A-frag regs (halves transient
        // pressure; offsets the +4 regs of xt4).
        HPack Ah, Ag;
        #pragma unroll
        for (int j2 = 0; j2 < 4; ++j2) {
            const float e0 = __builtin_amdgcn_exp2f(fmaf(tt, zwlo[2*j2],   zblo[2*j2]));
            const float e1 = __builtin_amdgcn_exp2f(fmaf(tt, zwlo[2*j2+1], zblo[2*j2+1]));
            const float r0 = __builtin_amdgcn_rcpf(e0 + 1.0f);
            const float r1 = __builtin_amdgcn_rcpf(e1 + 1.0f);
            const float h0 = fmaf(-2.0f, r0, 1.0f), h1 = fmaf(-2.0f, r1, 1.0f);
            const float g0 = fmaf(-h0, h0, 1.0f),   g1 = fmaf(-h1, h1, 1.0f);
            Ah.h2[j2] = __builtin_amdgcn_cvt_pkrtz(h0, h1);
            Ag.h2[j2] = __builtin_amdgcn_cvt_pkrtz(g0, g1);
        }
        lat = __builtin_amdgcn_mfma_f32_16x16x32_f16(Ah.h8, Blo.h8, lat, 0, 0, 0);
        dl  = __builtin_amdgcn_mfma_f32_16x16x32_f16(Ag.h8, Plo.h8, dl,  0, 0, 0);

        #pragma unroll
        for (int j2 = 0; j2 < 4; ++j2) {
            const float e0 = __builtin_amdgcn_exp2f(fmaf(tt, zwhi[2*j2],   zbhi[2*j2]));
            const float e1 = __builtin_amdgcn_exp2f(fmaf(tt, zwhi[2*j2+1], zbhi[2*j2+1]));
            const float r0 = __builtin_amdgcn_rcpf(e0 + 1.0f);
            const float r1 = __builtin_amdgcn_rcpf(e1 + 1.0f);
            const float h0 = fmaf(-2.0f, r0, 1.0f), h1 = fmaf(-2.0f, r1, 1.0f);
            const float g0 = fmaf(-h0, h0, 1.0f),   g1 = fmaf(-h1, h1, 1.0f);
            Ah.h2[j2] = __builtin_amdgcn_cvt_pkrtz(h0, h1);
            Ag.h2[j2] = __builtin_amdgcn_cvt_pkrtz(g0, g1);
        }
        lat = __builtin_amdgcn_mfma_f32_16x16x32_f16(Ah.h8, Bhi.h8, lat, 0, 0, 0);
        dl  = __builtin_amdgcn_mfma_f32_16x16x32_f16(Ag.h8, Phi.h8, dl,  0, 0, 0);

        // C/D: col = lane&15 (=n), row = quad*4 + reg (= point-in-tile).
        // Apply observables here (mu is lane-uniform: pp[mn]); accumulate
        // data loss in f32 (pre-f16-pack: closer to ref); store post-obs
        // (sv, dsv) for the physics transpose.
        const int rowbase = ti * 16 + 4 * q;
        const float xtr[4] = {xt4.x, xt4.y, xt4.z, xt4.w};
        #pragma unroll
        for (int r = 0; r < 4; ++r) {
            float sv  = lat[r];
            float dsv = dl[r];
            const float qm  = sv - mucol;
            const float svq = fmaxf(qm, 0.0f);
            const float dsq = qm > 0.0f ? dsv : 0.0f;   // relu' at 0 -> 0 (matches JAX)
            sv  = isq ? svq : sv;
            dsv = isq ? dsq : dsv;
            const float d = sv - xtr[r];
            dacc = fmaf(d, d, dacc);
            spk[(rowbase + r) * PSTRIDE + mn] = __builtin_amdgcn_cvt_pkrtz(sv, dsv);
        }
    }

    __syncthreads();   // vmcnt already drained (xt consumed in-tile) -> cheap

    // ---- epilogue: one thread per point; physics only (data loss done) ----
    RPack rp;
    {
        const uint4* pr = (const uint4*)&spk[lane * PSTRIDE];  // 80-B rows: 16B aligned
        #pragma unroll
        for (int c = 0; c < 4; ++c) rp.u4[c] = pr[c];
    }

    // unpack to f32 pairs: cols 0-7 = a/da (post-obs identity), 8-15 = xs/dxs
    // (post-relu/gate already applied in-tile)
    f32x2 av[4], dav[4], xv[4], dxv[4];
    #pragma unroll
    for (int j = 0; j < 4; ++j) {
        f32x2 t0 = { (float)rp.h2[2*j].x,   (float)rp.h2[2*j+1].x };
        f32x2 t1 = { (float)rp.h2[2*j].y,   (float)rp.h2[2*j+1].y };
        f32x2 t2 = { (float)rp.h2[8+2*j].x, (float)rp.h2[8+2*j+1].x };
        f32x2 t3 = { (float)rp.h2[8+2*j].y, (float)rp.h2[8+2*j+1].y };
        av[j] = t0; dav[j] = t1; xv[j] = t2; dxv[j] = t3;
    }

    // physics: rhs_a = g + Pi@x - a ; rhs_x = (Gamma@a)*(mu - x).
    // Packed f32x2 contraction -> v_pk_fma_f32; Pi/Gam wave-uniform scalar
    // loads (SGPR pairs).
    const float* Pi  = pp + 2 * N_;
    const float* Gam = pp + 2 * N_ + N_ * N_;
    float acc = 0.0f;
    #pragma unroll
    for (int i = 0; i < N_; ++i) {
        f32x2 s1v = {0.0f, 0.0f};
        f32x2 s2v = {0.0f, 0.0f};
        #pragma unroll
        for (int j = 0; j < 4; ++j) {
            f32x2 piv = { Pi[i * N_ + 2*j],  Pi[i * N_ + 2*j + 1] };
            f32x2 gav = { Gam[i * N_ + 2*j], Gam[i * N_ + 2*j + 1] };
            s1v = __builtin_elementwise_fma(piv, xv[j], s1v);
            s2v = __builtin_elementwise_fma(gav, av[j], s2v);
        }
        const float ai = av[i >> 1][i & 1];
        const float xi = xv[i >> 1][i & 1];
        const float s1 = (pp[i] - ai) + (s1v[0] + s1v[1]);
        const float d1 = dav[i >> 1][i & 1] - s1;
        acc = fmaf(d1, d1, acc);
        const float s2 = (s2v[0] + s2v[1]) * (pp[N_ + i] - xi);
        const float d2 = dxv[i >> 1][i & 1] - s2;
        acc = fmaf(d2, d2, acc);
    }

    // scale + wave reduce -> one partial per block (no atomics)
    float v = fmaf(acc + dacc, INV_MAIN, sup * INV_SUP);
    float w = wave_reduce(v);
    if (lane == 0) partials[blockIdx.y * gridDim.x + blockIdx.x] = w;
}

// one block of 1024: reduce NPART pre-scaled partials -> scalar
__global__ __launch_bounds__(FBLK)
void pinn_finalize_kernel(const float* __restrict__ partials,
                          float* __restrict__ out) {
    __shared__ float swsum[FBLK / 64];
    const int tid = threadIdx.x;

    const float4* p4 = (const float4*)partials;   // NPART/4 = 4096 float4s
    float v = 0.0f;
    #pragma unroll
    for (int c = 0; c < 4; ++c) {
        const float4 v4 = p4[tid + c * FBLK];
        v += (v4.x + v4.y) + (v4.z + v4.w);
    }

    float w = wave_reduce(v);
    if ((tid & 63) == 0) swsum[tid >> 6] = w;
    __syncthreads();
    if (tid == 0) {
        float s = 0.0f;
        #pragma unroll
        for (int i = 0; i < FBLK / 64; ++i) s += swsum[i];
        out[0] = s;
    }
}

extern "C" void kernel_launch(void* const* d_in, const int* in_sizes, int n_in,
                              void* d_out, int out_size, void* d_ws, size_t ws_size,
                              hipStream_t stream) {
    const float* t_in          = (const float*)d_in[0];
    const float* x_target      = (const float*)d_in[1];
    const float* params_pred   = (const float*)d_in[2];
    const float* params_target = (const float*)d_in[3];
    const float* ic_pred       = (const float*)d_in[4];
    const float* ic_target     = (const float*)d_in[5];
    const float* W1            = (const float*)d_in[6];
    const float* b1            = (const float*)d_in[7];
    const float* W2            = (const float*)d_in[8];
    const float* b2            = (const float*)d_in[9];
    float* out = (float*)d_out;
    float* partials = (float*)d_ws;   // NPART floats = 64 KB

    dim3 grid(NBLKX, B_);
    pinn_main_kernel<<<grid, WBLK, 0, stream>>>(t_in, x_target, params_pred,
                                                params_target, ic_pred, ic_target,
                                                W1, b1, W2, b2, partials);
    pinn_finalize_kernel<<<1, FBLK, 0, stream>>>(partials, out);
}

// Round 5
// 127.134 us; speedup vs baseline: 1.3877x; 1.3877x over previous
//
#include <hip/hip_runtime.h>
#include <math.h>

// Problem constants (match reference)
#define B_    256
#define T_    4096
#define N_    8        // n
#define TWON_ 16       // 2n
#define H_    64
#define P_    144      // 2n + 2n^2
#define WBLK  64                 // one wave per block
#define NBLKX (T_ / WBLK)        // 64 blocks along T
#define NPART (NBLKX * B_)       // 16384 partials
#define PSTRIDE 20               // LDS row stride in half2 units: 80 B rows, 16B-aligned
#define FBLK  1024               // finalize block size

// denominators
#define INV_MAIN  (1.0f / (float)(B_ * TWON_ * T_))   // 1/16777216
#define INV_SUP   (1.0f / (float)(B_ * (P_ + TWON_))) // 1/40960

#define TWO_LOG2E 2.8853900817779268f   // 2*log2(e): e^{2x} = 2^{x*TWO_LOG2E}

// ---- Session conclusions baked in (r1-r16) ----
// * 1-wave blocks, lb(64,6): best measured total (127.5-127.9 us).
// * HARD CONSTRAINT (r12 + r15, two strikes): ANY x_target access threaded
//   into the MFMA tile phase (prefetch batch OR per-tile "transient" float4 —
//   unroll hoisting makes it batch anyway) collapses the allocator:
//   VGPR_Count=40, 119-315 MB scratch writes, main 22 -> 84-139 us.
//   x_target loads stay strictly POST-MFMA, strided scalar, epilogue-consumed.
// * zw/zb weight tables stay in REGISTERS (r12: LDS version was half of the
//   collapse bundle). NEVER same-address atomicAdd from 16k blocks (r9).
// * r14 (verified 127.46 us): r0 structure + packed f32x2 physics epilogue.
//   Main kernel below top-5 (<40 us); fills at 78-83% HBM peak.
// * r16 (this): single-wave block -> __syncthreads() DELETED (DS ops are
//   in-order per wave; compiler inserts lgkmcnt before dependent ds_read).
//   This removes the s_waitcnt vmcnt(0)-before-s_barrier drain that forced
//   the 16 x_target loads to complete with zero cover. Epilogue reordered:
//   physics (LDS-derived) FIRST, data loss (xtv-dependent) LAST -> loads get
//   ~400+ cy of cover + 24-wave/CU TLP. Register pressure identical to r14.
// * Remaining total is harness-dominated: 268 MB ws poison fill (~40 us @ 83%
//   HBM peak), input restores, launch gaps. Main kernel vs its ~11 us
//   x_target-read floor is the only lever; if r16 is neutral -> ROOFLINE.

typedef __fp16   half2_t __attribute__((ext_vector_type(2)));  // cvt_pkrtz result type
typedef _Float16 half8_t __attribute__((ext_vector_type(8)));  // MFMA operand type
typedef float    f32x4   __attribute__((ext_vector_type(4)));
typedef float    f32x2   __attribute__((ext_vector_type(2)));

union HPack { half2_t h2[4]; half8_t h8; };   // MFMA operand pun
union RPack { uint4 u4[4]; half2_t h2[16]; }; // LDS row read pun (64 B)

__device__ __forceinline__ float wave_reduce(float v) {
    #pragma unroll
    for (int off = 32; off > 0; off >>= 1) v += __shfl_down(v, off, 64);
    return v;
}

__global__ __launch_bounds__(WBLK, 6)
void pinn_main_kernel(const float* __restrict__ t_in,
                      const float* __restrict__ x_target,
                      const float* __restrict__ params_pred,
                      const float* __restrict__ params_target,
                      const float* __restrict__ ic_pred,
                      const float* __restrict__ ic_target,
                      const float* __restrict__ W1,
                      const float* __restrict__ b1,
                      const float* __restrict__ W2,
                      const float* __restrict__ b2,
                      float* __restrict__ partials) {
    __shared__ __align__(16) half2_t spk[WBLK * PSTRIDE];  // 5.1 KB: (lat, dlat) packed

    const int lane = threadIdx.x;    // 0..63
    const int b    = blockIdx.y;
    const int q    = lane >> 4;      // quad
    const int mn   = lane & 15;      // A-row (point-in-tile) == B/C col n
    const int k0   = q * 8;          // this lane's k-group base (within K=32 half)

    const float* pp = params_pred + b * P_;   // uniform -> scalar loads
    const int tq = blockIdx.x * WBLK + lane;

    // ---- supervised loss (blocks with x==0; one per batch) ----
    float sup = 0.0f;
    if (blockIdx.x == 0) {
        #pragma unroll
        for (int i = lane; i < P_; i += WBLK) {   // 144 elems
            const float d = pp[i] - params_target[b * P_ + i];
            sup = fmaf(d, d, sup);
        }
        if (lane < TWON_) {
            const float d = ic_pred[b * TWON_ + lane] - ic_target[b * TWON_ + lane];
            sup = fmaf(d, d, sup);
        }
    }

    // ---- per-lane weight setup (REGISTERS — r12 lesson: not LDS) ----
    // E = e^{2x} = exp2(x*2log2e); tanh = 1 - 2/(E+1). exp2 limits give h=+-1, g=0.
    float zwlo[8], zblo[8], zwhi[8], zbhi[8];
    HPack Blo, Bhi, Plo, Phi;   // B[k][n]=W2[k][n]; B'[k][n]=W1[k]*W2[k][n]
    #pragma unroll
    for (int j2 = 0; j2 < 4; ++j2) {
        const int ka = k0 + 2 * j2, kb = ka + 1;
        const float w1a = W1[ka],      w1b = W1[kb];
        const float w1c = W1[32 + ka], w1d = W1[32 + kb];
        zwlo[2*j2] = TWO_LOG2E * w1a; zwlo[2*j2+1] = TWO_LOG2E * w1b;
        zwhi[2*j2] = TWO_LOG2E * w1c; zwhi[2*j2+1] = TWO_LOG2E * w1d;
        zblo[2*j2] = TWO_LOG2E * b1[ka];      zblo[2*j2+1] = TWO_LOG2E * b1[kb];
        zbhi[2*j2] = TWO_LOG2E * b1[32 + ka]; zbhi[2*j2+1] = TWO_LOG2E * b1[32 + kb];
        const float wa = W2[ka * TWON_ + mn],        wb = W2[kb * TWON_ + mn];
        const float wc = W2[(32 + ka) * TWON_ + mn], wd = W2[(32 + kb) * TWON_ + mn];
        Blo.h2[j2] = __builtin_amdgcn_cvt_pkrtz(wa, wb);
        Bhi.h2[j2] = __builtin_amdgcn_cvt_pkrtz(wc, wd);
        Plo.h2[j2] = __builtin_amdgcn_cvt_pkrtz(w1a * wa, w1b * wb);
        Phi.h2[j2] = __builtin_amdgcn_cvt_pkrtz(w1c * wc, w1d * wd);
    }
    const float b2n = b2[mn];

    // t for this wave's 64 points
    const float treg = t_in[b * T_ + tq];

    // ---- 4 tiles of 16 points each ----
    #pragma unroll
    for (int ti = 0; ti < 4; ++ti) {
        const float tt = __shfl(treg, ti * 16 + mn, 64);

        HPack Ah_lo, Ag_lo, Ah_hi, Ag_hi;
        #pragma unroll
        for (int j2 = 0; j2 < 4; ++j2) {
            // low half (k = k0+2j2, k0+2j2+1)
            float e0 = __builtin_amdgcn_exp2f(fmaf(tt, zwlo[2*j2],   zblo[2*j2]));
            float e1 = __builtin_amdgcn_exp2f(fmaf(tt, zwlo[2*j2+1], zblo[2*j2+1]));
            float r0 = __builtin_amdgcn_rcpf(e0 + 1.0f);
            float r1 = __builtin_amdgcn_rcpf(e1 + 1.0f);
            float h0 = fmaf(-2.0f, r0, 1.0f), h1 = fmaf(-2.0f, r1, 1.0f);
            float g0 = fmaf(-h0, h0, 1.0f),   g1 = fmaf(-h1, h1, 1.0f);
            Ah_lo.h2[j2] = __builtin_amdgcn_cvt_pkrtz(h0, h1);
            Ag_lo.h2[j2] = __builtin_amdgcn_cvt_pkrtz(g0, g1);
            // high half (k+32)
            e0 = __builtin_amdgcn_exp2f(fmaf(tt, zwhi[2*j2],   zbhi[2*j2]));
            e1 = __builtin_amdgcn_exp2f(fmaf(tt, zwhi[2*j2+1], zbhi[2*j2+1]));
            r0 = __builtin_amdgcn_rcpf(e0 + 1.0f);
            r1 = __builtin_amdgcn_rcpf(e1 + 1.0f);
            h0 = fmaf(-2.0f, r0, 1.0f); h1 = fmaf(-2.0f, r1, 1.0f);
            g0 = fmaf(-h0, h0, 1.0f);   g1 = fmaf(-h1, h1, 1.0f);
            Ah_hi.h2[j2] = __builtin_amdgcn_cvt_pkrtz(h0, h1);
            Ag_hi.h2[j2] = __builtin_amdgcn_cvt_pkrtz(g0, g1);
        }

        f32x4 lat = {b2n, b2n, b2n, b2n};
        lat = __builtin_amdgcn_mfma_f32_16x16x32_f16(Ah_lo.h8, Blo.h8, lat, 0, 0, 0);
        lat = __builtin_amdgcn_mfma_f32_16x16x32_f16(Ah_hi.h8, Bhi.h8, lat, 0, 0, 0);
        f32x4 dl = {0.0f, 0.0f, 0.0f, 0.0f};
        dl = __builtin_amdgcn_mfma_f32_16x16x32_f16(Ag_lo.h8, Plo.h8, dl, 0, 0, 0);
        dl = __builtin_amdgcn_mfma_f32_16x16x32_f16(Ag_hi.h8, Phi.h8, dl, 0, 0, 0);

        // C/D: col = lane&15 (=n), row = quad*4 + reg (= point-in-tile)
        const int rowbase = ti * 16 + 4 * q;
        #pragma unroll
        for (int r = 0; r < 4; ++r) {
            spk[(rowbase + r) * PSTRIDE + mn] = __builtin_amdgcn_cvt_pkrtz(lat[r], dl[r]);
        }
    }

    // ---- x_target loads: issued post-MFMA (hard constraint r12/r15).
    // NO barrier after these: single-wave block, DS write->read ordering is
    // per-wave in-order + compiler lgkmcnt. The loads stay in flight through
    // the LDS round-trip + physics below; consumed LAST (data loss). ----
    const float* xt = x_target + (size_t)b * TWON_ * T_ + tq;
    float xtv[TWON_];
    #pragma unroll
    for (int k = 0; k < TWON_; ++k) xtv[k] = xt[(size_t)k * T_];

    // ---- epilogue: one thread per point ----
    float lat[TWON_], dlat[TWON_];
    {
        RPack rp;
        const uint4* pr = (const uint4*)&spk[lane * PSTRIDE];  // 80-B rows: 16B aligned
        #pragma unroll
        for (int c = 0; c < 4; ++c) rp.u4[c] = pr[c];
        #pragma unroll
        for (int i = 0; i < TWON_; ++i) { lat[i] = (float)rp.h2[i].x; dlat[i] = (float)rp.h2[i].y; }
    }

    float a[N_], xs[N_], da_[N_], dxs[N_];
    #pragma unroll
    for (int i = 0; i < N_; ++i) { a[i] = lat[i]; da_[i] = dlat[i]; }
    #pragma unroll
    for (int i = 0; i < N_; ++i) {
        const float qm = lat[N_ + i] - pp[N_ + i];   // mu: scalar load
        xs[i]  = qm > 0.0f ? qm : 0.0f;
        dxs[i] = qm > 0.0f ? dlat[N_ + i] : 0.0f;
    }

    // physics FIRST (LDS-derived only): rhs_a = g + Pi@x - a ;
    // rhs_x = (Gamma@a)*(mu - x). Packed f32x2 -> v_pk_fma_f32; Pi/Gam are
    // wave-uniform scalar loads (SGPR pairs).
    f32x2 av[4], xv[4];
    #pragma unroll
    for (int j = 0; j < 4; ++j) {
        f32x2 ta = { a[2*j],  a[2*j+1]  };
        f32x2 tx = { xs[2*j], xs[2*j+1] };
        av[j] = ta; xv[j] = tx;
    }
    const float* Pi  = pp + 2 * N_;
    const float* Gam = pp + 2 * N_ + N_ * N_;
    float acc = 0.0f;
    #pragma unroll
    for (int i = 0; i < N_; ++i) {
        f32x2 s1v = {0.0f, 0.0f};
        f32x2 s2v = {0.0f, 0.0f};
        #pragma unroll
        for (int j = 0; j < 4; ++j) {
            f32x2 piv = { Pi[i * N_ + 2*j],  Pi[i * N_ + 2*j + 1] };
            f32x2 gav = { Gam[i * N_ + 2*j], Gam[i * N_ + 2*j + 1] };
            s1v = __builtin_elementwise_fma(piv, xv[j], s1v);
            s2v = __builtin_elementwise_fma(gav, av[j], s2v);
        }
        const float s1 = (pp[i] - a[i]) + (s1v[0] + s1v[1]);
        const float d1 = da_[i] - s1;
        acc = fmaf(d1, d1, acc);
        const float s2 = (s2v[0] + s2v[1]) * (pp[N_ + i] - xs[i]);
        const float d2 = dxs[i] - s2;
        acc = fmaf(d2, d2, acc);
    }

    // data loss LAST: first (and only) use of xtv -> vmcnt waits land here,
    // covered by everything above.
    #pragma unroll
    for (int k = 0; k < N_; ++k) { const float d = a[k]  - xtv[k];      acc = fmaf(d, d, acc); }
    #pragma unroll
    for (int k = 0; k < N_; ++k) { const float d = xs[k] - xtv[N_ + k]; acc = fmaf(d, d, acc); }

    // scale + wave reduce -> one partial per block (no atomics)
    float v = fmaf(acc, INV_MAIN, sup * INV_SUP);
    float w = wave_reduce(v);
    if (lane == 0) partials[blockIdx.y * gridDim.x + blockIdx.x] = w;
}

// one block of 1024: reduce NPART pre-scaled partials -> scalar
__global__ __launch_bounds__(FBLK)
void pinn_finalize_kernel(const float* __restrict__ partials,
                          float* __restrict__ out) {
    __shared__ float swsum[FBLK / 64];
    const int tid = threadIdx.x;

    const float4* p4 = (const float4*)partials;   // NPART/4 = 4096 float4s
    float v = 0.0f;
    #pragma unroll
    for (int c = 0; c < 4; ++c) {
        const float4 v4 = p4[tid + c * FBLK];
        v += (v4.x + v4.y) + (v4.z + v4.w);
    }

    float w = wave_reduce(v);
    if ((tid & 63) == 0) swsum[tid >> 6] = w;
    __syncthreads();
    if (tid == 0) {
        float s = 0.0f;
        #pragma unroll
        for (int i = 0; i < FBLK / 64; ++i) s += swsum[i];
        out[0] = s;
    }
}

extern "C" void kernel_launch(void* const* d_in, const int* in_sizes, int n_in,
                              void* d_out, int out_size, void* d_ws, size_t ws_size,
                              hipStream_t stream) {
    const float* t_in          = (const float*)d_in[0];
    const float* x_target      = (const float*)d_in[1];
    const float* params_pred   = (const float*)d_in[2];
    const float* params_target = (const float*)d_in[3];
    const float* ic_pred       = (const float*)d_in[4];
    const float* ic_target     = (const float*)d_in[5];
    const float* W1            = (const float*)d_in[6];
    const float* b1            = (const float*)d_in[7];
    const float* W2            = (const float*)d_in[8];
    const float* b2            = (const float*)d_in[9];
    float* out = (float*)d_out;
    float* partials = (float*)d_ws;   // NPART floats = 64 KB

    dim3 grid(NBLKX, B_);
    pinn_main_kernel<<<grid, WBLK, 0, stream>>>(t_in, x_target, params_pred,
                                                params_target, ic_pred, ic_target,
                                                W1, b1, W2, b2, partials);
    pinn_finalize_kernel<<<1, FBLK, 0, stream>>>(partials, out);
}